// Round 1
// baseline (359.872 us; speedup 1.0000x reference)
//
#include <hip/hip_runtime.h>

// FocalLoss (RetinaNet-style) on MI355X.
// Inputs (fp32): classifications (8,49104,90), regressions (8,49104,4),
//                anchors (1,49104,4), annotations (8,32,5)
// Output: 2 fp32 scalars (clf_loss, reg_loss).

namespace {
constexpr int B_N = 8;
constexpr int A_N = 49104;
constexpr int C_N = 90;
constexpr int M_N = 32;
constexpr float EPSF   = 1e-4f;
constexpr float ACCEPT = 0.5f;
constexpr float REJECT = 0.4f;
constexpr float SL1R   = 9.0f;
constexpr float CLFW   = 1.0f;
constexpr float REGW   = 50.0f;

__device__ __forceinline__ float focal_term(float x, bool is_pos) {
    // pos: 0.25*(1-x)^2 * -log(x);  neg: 0.75*x^2 * -log(1-x)
    // unified: y = is_pos ? x : 1-x;  a*(1-y)^2*(-log y)
    x = fminf(fmaxf(x, EPSF), 1.0f - EPSF);
    float y  = is_pos ? x : 1.0f - x;
    float al = is_pos ? 0.25f : 0.75f;
    float omy = 1.0f - y;
    return al * omy * omy * (-__logf(y));
}
} // namespace

// ---------------- kernel 1: match + reg loss ----------------
// grid (ceil(A/256), B), block 256. One thread per anchor.
__global__ void match_kernel(const float* __restrict__ anchors,
                             const float* __restrict__ reg,
                             const float* __restrict__ ann,
                             int*   __restrict__ state,    // [B*A]
                             int*   __restrict__ nm,       // [B]
                             float* __restrict__ reg_sum)  // [B]
{
    __shared__ float sann[M_N * 5];
    const int b   = blockIdx.y;
    const int tid = threadIdx.x;
    if (tid < M_N * 5) sann[tid] = ann[b * M_N * 5 + tid];
    __syncthreads();

    const int i = blockIdx.x * blockDim.x + tid;
    int   cnt  = 0;
    float rsum = 0.0f;

    if (i < A_N) {
        const float4 av = ((const float4*)anchors)[i];
        const float ay1 = av.x, ax1 = av.y, ay2 = av.z, ax2 = av.w;
        const float aw = ax2 - ax1, ah = ay2 - ay1;
        const float aarea = aw * ah;

        float best = -3.4e38f;
        int   arg  = 0;
        #pragma unroll 8
        for (int j = 0; j < M_N; ++j) {
            const float bx1 = sann[j*5+0], by1 = sann[j*5+1];
            const float bx2 = sann[j*5+2], by2 = sann[j*5+3];
            const float lb  = sann[j*5+4];
            float iw = fminf(ax2, bx2) - fmaxf(ax1, bx1); iw = fmaxf(iw, 0.0f);
            float ih = fminf(ay2, by2) - fmaxf(ay1, by1); ih = fmaxf(ih, 0.0f);
            const float inter = iw * ih;
            const float barea = (bx2 - bx1) * (by2 - by1);
            const float uni   = fmaxf(aarea + barea - inter, 1e-8f);
            float iou = inter / uni;
            if (lb == -1.0f) iou = -1.0f;
            if (iou > best) { best = iou; arg = j; } // first-occurrence argmax
        }

        const bool matched   = best > ACCEPT;
        const bool unmatched = best < REJECT;
        int s;
        if (matched) {
            s   = (int)sann[arg*5+4] - 1;   // class index 0..89
            cnt = 1;
            // regression target from matched box
            const float bx1 = sann[arg*5+0], by1 = sann[arg*5+1];
            const float bx2 = sann[arg*5+2], by2 = sann[arg*5+3];
            const float gwr = bx2 - bx1, ghr = by2 - by1;
            const float gcx = bx1 + 0.5f * gwr, gcy = by1 + 0.5f * ghr;
            const float gw  = fmaxf(gwr, 1.0f), gh = fmaxf(ghr, 1.0f);
            const float acx = ax1 + 0.5f * aw, acy = ay1 + 0.5f * ah;
            const float t0 = (gcy - acy) / ah;
            const float t1 = (gcx - acx) / aw;
            const float t2 = __logf(gh / ah);
            const float t3 = __logf(gw / aw);
            const float4 rv = ((const float4*)reg)[b * A_N + i];
            float d;
            d = fabsf(SL1R * (rv.x - t0)); rsum += (d < 1.0f) ? 0.5f*d*d : d - 0.5f;
            d = fabsf(SL1R * (rv.y - t1)); rsum += (d < 1.0f) ? 0.5f*d*d : d - 0.5f;
            d = fabsf(SL1R * (rv.z - t2)); rsum += (d < 1.0f) ? 0.5f*d*d : d - 0.5f;
            d = fabsf(SL1R * (rv.w - t3)); rsum += (d < 1.0f) ? 0.5f*d*d : d - 0.5f;
        } else {
            s = unmatched ? -1 : -2;
        }
        state[b * A_N + i] = s;
    }

    // wave(64) reduce, one atomic per wave
    #pragma unroll
    for (int off = 32; off > 0; off >>= 1) {
        cnt  += __shfl_down(cnt,  off);
        rsum += __shfl_down(rsum, off);
    }
    if ((tid & 63) == 0) {
        if (cnt)         atomicAdd(&nm[b], cnt);
        if (rsum != 0.f) atomicAdd(&reg_sum[b], rsum);
    }
}

// ---------------- kernel 2: classification focal loss ----------------
// grid (BPI, B), block 256, float4 grid-stride over one image's clf.
__global__ void clf_kernel(const float* __restrict__ clf,
                           const int*   __restrict__ state,
                           float*       __restrict__ clf_sum)  // [B]
{
    constexpr unsigned F4 = (unsigned)(A_N * C_N) / 4u; // 1,104,840
    const int b = blockIdx.y;
    const float4* __restrict__ p  = (const float4*)(clf + (size_t)b * A_N * C_N);
    const int*    __restrict__ st = state + b * A_N;

    float sum = 0.0f;
    const unsigned stride = gridDim.x * blockDim.x;
    for (unsigned f = blockIdx.x * blockDim.x + threadIdx.x; f < F4; f += stride) {
        const float4 v = p[f];
        const unsigned idx = 4u * f;         // element index within image
        const unsigned a   = idx / 90u;      // anchor (magic-mul)
        const unsigned c0  = idx - a * 90u;  // class of v.x; always even
        if (c0 != 88u) {
            const int s = st[a];
            if (s != -2) {  // not ignored
                sum += focal_term(v.x, s == (int)c0);
                sum += focal_term(v.y, s == (int)c0 + 1);
                sum += focal_term(v.z, s == (int)c0 + 2);
                sum += focal_term(v.w, s == (int)c0 + 3);
            }
        } else {
            // straddles anchors a (classes 88,89) and a+1 (classes 0,1)
            const int s1 = st[a];
            const int s2 = st[a + 1];
            if (s1 != -2) {
                sum += focal_term(v.x, s1 == 88);
                sum += focal_term(v.y, s1 == 89);
            }
            if (s2 != -2) {
                sum += focal_term(v.z, s2 == 0);
                sum += focal_term(v.w, s2 == 1);
            }
        }
    }

    #pragma unroll
    for (int off = 32; off > 0; off >>= 1) sum += __shfl_down(sum, off);
    if ((threadIdx.x & 63) == 0) atomicAdd(&clf_sum[b], sum);
}

// ---------------- kernel 3: finalize ----------------
__global__ void finalize_kernel(const int*   __restrict__ nm,
                                const float* __restrict__ clf_sum,
                                const float* __restrict__ reg_sum,
                                float*       __restrict__ out)
{
    if (threadIdx.x == 0 && blockIdx.x == 0) {
        float cl = 0.0f, rl = 0.0f;
        for (int b = 0; b < B_N; ++b) {
            const int n = nm[b];
            const float dclf = (float)(n > 1 ? n : 1);
            cl += clf_sum[b] / dclf;
            if (n > 0) rl += reg_sum[b] / (float)(4 * n);
        }
        out[0] = CLFW * (cl / (float)B_N);
        out[1] = REGW * (rl / (float)B_N);
    }
}

extern "C" void kernel_launch(void* const* d_in, const int* in_sizes, int n_in,
                              void* d_out, int out_size, void* d_ws, size_t ws_size,
                              hipStream_t stream) {
    const float* clf     = (const float*)d_in[0];
    const float* reg     = (const float*)d_in[1];
    const float* anchors = (const float*)d_in[2];
    const float* ann     = (const float*)d_in[3];
    float* out = (float*)d_out;

    char* ws = (char*)d_ws;
    int*   nm      = (int*)(ws + 0);     // 8 ints
    float* clf_sum = (float*)(ws + 64);  // 8 floats
    float* reg_sum = (float*)(ws + 128); // 8 floats
    int*   state   = (int*)(ws + 256);   // B*A ints = 1.57 MB

    // zero the accumulators (ws is poisoned 0xAA before each call)
    hipMemsetAsync(d_ws, 0, 256, stream);

    {
        dim3 grid((A_N + 255) / 256, B_N);
        match_kernel<<<grid, 256, 0, stream>>>(anchors, reg, ann, state, nm, reg_sum);
    }
    {
        dim3 grid(256, B_N);  // 2048 blocks x 256 threads
        clf_kernel<<<grid, 256, 0, stream>>>(clf, state, clf_sum);
    }
    finalize_kernel<<<1, 64, 0, stream>>>(nm, clf_sum, reg_sum, out);
}